// Round 1
// baseline (1376.997 us; speedup 1.0000x reference)
//
#include <hip/hip_runtime.h>
#include <hip/hip_bf16.h>

#define HH 32
#define WW 64
#define HWSZ 2048
#define HID 256
#define ENC 1024
#define VOCAB 5000

__device__ __forceinline__ float bf2f(unsigned short u) {
    union { unsigned i; float f; } x; x.i = ((unsigned)u) << 16; return x.f;
}
__device__ __forceinline__ float sigm(float x) { return 1.0f / (1.0f + expf(-x)); }

// ---------------- K1: emb gather + GRU1 + fc1 (hidden1). One block per batch. ----
__global__ __launch_bounds__(256) void k_front(
    const int* __restrict__ input_a, const float* __restrict__ input_hidden,
    const float* __restrict__ emb_w,
    const float* __restrict__ w_ih, const float* __restrict__ w_hh,
    const float* __restrict__ b_ih, const float* __restrict__ b_hh,
    const float* __restrict__ fc1_w, const float* __restrict__ fc1_b,
    float* __restrict__ ws_st, float* __restrict__ ws_emb, float* __restrict__ ws_h1)
{
    __shared__ float emb_s[256], h0_s[256], gi_s[768], gh_s[768], st_s[256];
    int b = blockIdx.x, t = threadIdx.x;
    int ia = input_a[b];
    float ev = emb_w[ia * 256 + t];
    emb_s[t] = ev;
    ws_emb[b * 256 + t] = ev;
    h0_s[t] = input_hidden[b * 256 + t];
    __syncthreads();
    for (int j = t; j < 768; j += 256) {
        const float* wi = w_ih + j * 256;
        const float* wh = w_hh + j * 256;
        float si = 0.f, sh = 0.f;
        for (int k = 0; k < 256; ++k) { si += emb_s[k] * wi[k]; sh += h0_s[k] * wh[k]; }
        gi_s[j] = si + b_ih[j];
        gh_s[j] = sh + b_hh[j];
    }
    __syncthreads();
    {
        int i = t;
        float r = sigm(gi_s[i] + gh_s[i]);
        float z = sigm(gi_s[256 + i] + gh_s[256 + i]);
        float n = tanhf(gi_s[512 + i] + r * gh_s[512 + i]);
        float v = (1.f - z) * n + z * h0_s[i];
        st_s[i] = v;
        ws_st[b * 256 + i] = v;
    }
    __syncthreads();
    {
        int c = t;
        const float* w = fc1_w + c * 256;
        float s = fc1_b[c];
        for (int k = 0; k < 256; ++k) s += st_s[k] * w[k];
        ws_h1[b * 256 + c] = s;
    }
}

// ---------------- K2: att_sum = attention_sum + conv3x3(decoder_attention) ------
__global__ __launch_bounds__(256) void k_attsum(
    const float* __restrict__ att_in, const float* __restrict__ dec,
    const float* __restrict__ c1w, const float* __restrict__ c1b,
    float* __restrict__ out_attsum)
{
    int idx = blockIdx.x * 256 + threadIdx.x;  // < 32768
    int b = idx >> 11, hw = idx & 2047;
    int h = hw >> 6, w = hw & 63;
    float s = c1b[0];
    #pragma unroll
    for (int dy = 0; dy < 3; ++dy) {
        int hh = h + dy - 1;
        if ((unsigned)hh < (unsigned)HH) {
            #pragma unroll
            for (int dx = 0; dx < 3; ++dx) {
                int wi = w + dx - 1;
                if ((unsigned)wi < (unsigned)WW)
                    s += dec[b * HWSZ + hh * WW + wi] * c1w[dy * 3 + dx];
            }
        }
    }
    out_attsum[idx] = att_in[idx] + s;
}

// ---------------- K3: et = UA@enc + hidden1 + ua_b + uf_b + attsum*uf_w  (bf16, NCHW)
// Per batch: OUT[c, hw] (256 x 2048), K=1024. Tile 64x64, BK=16, 256 thr, 4x4/thread.
__global__ __launch_bounds__(256) void k_et(
    const float* __restrict__ enc, const float* __restrict__ ua_w,
    const float* __restrict__ ua_b, const float* __restrict__ uf_w,
    const float* __restrict__ uf_b, const float* __restrict__ h1,
    const float* __restrict__ attsum, __hip_bfloat16* __restrict__ et)
{
    __shared__ float As[16][64];  // [k][c]
    __shared__ float Bs[16][64];  // [k][hw]
    int t = threadIdx.x;
    int ty = t >> 4, tx = t & 15;
    int hw0 = blockIdx.x * 64, c0 = blockIdx.y * 64, b = blockIdx.z;
    float acc[4][4] = {};
    int a_c = t >> 2, a_k = (t & 3) * 4;
    int b_k = t >> 4, b_w = (t & 15) * 4;
    for (int k0 = 0; k0 < ENC; k0 += 16) {
        float4 av = *(const float4*)(ua_w + (size_t)(c0 + a_c) * ENC + k0 + a_k);
        float4 bv = *(const float4*)(enc + ((size_t)(b * ENC + k0 + b_k)) * HWSZ + hw0 + b_w);
        As[a_k + 0][a_c] = av.x; As[a_k + 1][a_c] = av.y;
        As[a_k + 2][a_c] = av.z; As[a_k + 3][a_c] = av.w;
        *(float4*)&Bs[b_k][b_w] = bv;
        __syncthreads();
        #pragma unroll
        for (int k = 0; k < 16; ++k) {
            float4 a = *(const float4*)&As[k][ty * 4];
            float4 bb = *(const float4*)&Bs[k][tx * 4];
            acc[0][0] += a.x * bb.x; acc[0][1] += a.x * bb.y; acc[0][2] += a.x * bb.z; acc[0][3] += a.x * bb.w;
            acc[1][0] += a.y * bb.x; acc[1][1] += a.y * bb.y; acc[1][2] += a.y * bb.z; acc[1][3] += a.y * bb.w;
            acc[2][0] += a.z * bb.x; acc[2][1] += a.z * bb.y; acc[2][2] += a.z * bb.z; acc[2][3] += a.z * bb.w;
            acc[3][0] += a.w * bb.x; acc[3][1] += a.w * bb.y; acc[3][2] += a.w * bb.z; acc[3][3] += a.w * bb.w;
        }
        __syncthreads();
    }
    #pragma unroll
    for (int i = 0; i < 4; ++i) {
        int c = c0 + ty * 4 + i;
        float addc = h1[b * 256 + c] + ua_b[c] + uf_b[c];
        float ufw = uf_w[c];
        #pragma unroll
        for (int j = 0; j < 4; ++j) {
            int hw = hw0 + tx * 4 + j;
            float at = attsum[b * HWSZ + hw];
            float v = acc[i][j] + addc + at * ufw;
            et[((size_t)(b * 256 + c)) * HWSZ + hw] = __float2bfloat16(v);
        }
    }
}

// ---------------- K4: conv3x3(et) + bias + BN + tanh + dot(v_w) -> partial e ----
// Block: one h row (64 w) x 64 c_out; K-loop over (c_in chunk of 16) x 9 taps.
__global__ __launch_bounds__(256) void k_conv(
    const __hip_bfloat16* __restrict__ et, const float* __restrict__ wt,
    const float* __restrict__ wb, const float* __restrict__ bn_g,
    const float* __restrict__ bn_b, const float* __restrict__ bn_rm,
    const float* __restrict__ bn_rv, const float* __restrict__ v_w,
    float* __restrict__ e_acc)
{
    __shared__ float As[144][64];   // [ci*9+tap][c_out]  36.9 KB
    __shared__ float in_s[48][66];  // [dy*16+ci][w+1], cols 0 & 65 are zero pad  12.7 KB
    int t = threadIdx.x;
    int ty = t >> 4, tx = t & 15;
    int h = blockIdx.x, c0 = blockIdx.y * 64, b = blockIdx.z;
    float acc[4][4] = {};
    int co = t >> 2, q = t & 3;
    for (int ci0 = 0; ci0 < 256; ci0 += 16) {
        __syncthreads();
        // stage input: 48 rows (3 dy x 16 ci) x 64 w (bf16 -> f32), zero halo
        for (int s = t; s < 768; s += 256) {
            int r = s >> 4, lane = s & 15;
            int dy = r >> 4, ci = r & 15;
            int hrow = h + dy - 1;
            int w4 = lane * 4;
            float v0 = 0.f, v1 = 0.f, v2 = 0.f, v3 = 0.f;
            if ((unsigned)hrow < (unsigned)HH) {
                const unsigned short* p = (const unsigned short*)et +
                    ((size_t)(b * 256 + ci0 + ci) * HH + hrow) * WW + w4;
                ushort4 u = *(const ushort4*)p;
                v0 = bf2f(u.x); v1 = bf2f(u.y); v2 = bf2f(u.z); v3 = bf2f(u.w);
            }
            float* row = in_s[r];
            row[1 + w4] = v0; row[2 + w4] = v1; row[3 + w4] = v2; row[4 + w4] = v3;
            if (lane == 0) { row[0] = 0.f; row[65] = 0.f; }
        }
        // stage weights: As[kk][co], kk = ci_local*9 + tap
        {
            const float* wp = wt + (size_t)(c0 + co) * 2304 + ci0 * 9;
            #pragma unroll
            for (int u = 0; u < 36; ++u) {
                int kk = q * 36 + u;
                As[kk][co] = wp[kk];
            }
        }
        __syncthreads();
        #pragma unroll 1
        for (int ci = 0; ci < 16; ++ci) {
            #pragma unroll
            for (int dy = 0; dy < 3; ++dy) {
                const float* row = &in_s[(dy << 4) + ci][tx * 4];
                float bv[6];
                #pragma unroll
                for (int u = 0; u < 6; ++u) bv[u] = row[u];
                int kbase = ci * 9 + dy * 3;
                #pragma unroll
                for (int dx = 0; dx < 3; ++dx) {
                    float4 a = *(const float4*)&As[kbase + dx][ty * 4];
                    #pragma unroll
                    for (int j = 0; j < 4; ++j) {
                        float bb = bv[j + dx];
                        acc[0][j] += a.x * bb;
                        acc[1][j] += a.y * bb;
                        acc[2][j] += a.z * bb;
                        acc[3][j] += a.w * bb;
                    }
                }
            }
        }
    }
    // epilogue: bias + BN + tanh + v-dot, reduce over c within block
    __syncthreads();
    float* red = &in_s[0][0];  // reuse: 16 x 64 floats
    float p[4] = {0.f, 0.f, 0.f, 0.f};
    #pragma unroll
    for (int i = 0; i < 4; ++i) {
        int c = c0 + ty * 4 + i;
        float inv = bn_g[c] * rsqrtf(bn_rv[c] + 1e-5f);
        float bias = wb[c], rm = bn_rm[c], bb = bn_b[c], vw = v_w[c];
        #pragma unroll
        for (int j = 0; j < 4; ++j) {
            float x = acc[i][j] + bias;
            x = (x - rm) * inv + bb;
            p[j] += tanhf(x) * vw;
        }
    }
    #pragma unroll
    for (int j = 0; j < 4; ++j) red[ty * 64 + tx * 4 + j] = p[j];
    __syncthreads();
    if (t < 64) {
        float s = 0.f;
        #pragma unroll
        for (int yy = 0; yy < 16; ++yy) s += red[yy * 64 + t];
        atomicAdd(&e_acc[(b * HH + h) * WW + t], s);
    }
}

// ---------------- K5: softmax over masked e -> alpha (ws + d_out) ---------------
__global__ __launch_bounds__(256) void k_alpha(
    const float* __restrict__ e_acc, const float* __restrict__ v_b,
    const int* __restrict__ h_mask, const int* __restrict__ w_mask,
    float* __restrict__ alpha_ws, float* __restrict__ alpha_out)
{
    __shared__ float rbuf[4];
    int b = blockIdx.x, t = threadIdx.x;
    int hm = h_mask[b], wm = w_mask[b];
    float vb = v_b[0];
    float vals[8];
    float psum = 0.f;
    #pragma unroll
    for (int u = 0; u < 8; ++u) {
        int s = u * 256 + t;
        int h = s >> 6, w = s & 63;
        float e = e_acc[b * HWSZ + s] + vb;
        float ex = (h < hm && w < wm) ? expf(e) : 0.f;
        vals[u] = ex;
        psum += ex;
    }
    for (int off = 1; off < 64; off <<= 1) psum += __shfl_xor(psum, off, 64);
    if ((t & 63) == 0) rbuf[t >> 6] = psum;
    __syncthreads();
    float tot = rbuf[0] + rbuf[1] + rbuf[2] + rbuf[3] + 1e-8f;
    float inv = 1.f / tot;
    #pragma unroll
    for (int u = 0; u < 8; ++u) {
        int s = u * 256 + t;
        float a = vals[u] * inv;
        alpha_ws[b * HWSZ + s] = a;
        alpha_out[b * HWSZ + s] = a;
    }
}

// ---------------- K6: ct[b,c] = sum_hw alpha * enc  (wave per channel) ----------
__global__ __launch_bounds__(256) void k_ct(
    const float* __restrict__ enc, const float* __restrict__ alpha,
    float* __restrict__ ct)
{
    __shared__ float a_s[HWSZ];
    int b = blockIdx.y, cg = blockIdx.x, t = threadIdx.x;
    for (int s = t; s < HWSZ; s += 256) a_s[s] = alpha[b * HWSZ + s];
    __syncthreads();
    int wave = t >> 6, lane = t & 63;
    int c = cg * 4 + wave;
    const float* ep = enc + ((size_t)(b * ENC + c)) * HWSZ;
    float s = 0.f;
    for (int i = lane; i < HWSZ; i += 64) s += ep[i] * a_s[i];
    for (int off = 32; off; off >>= 1) s += __shfl_down(s, off, 64);
    if (lane == 0) ct[b * ENC + c] = s;
}

// ---------------- K7: GRU2(ct, st) -> h2, hidden_next ---------------------------
__global__ __launch_bounds__(256) void k_gru2(
    const float* __restrict__ ct, const float* __restrict__ st,
    const float* __restrict__ w_ih, const float* __restrict__ w_hh,
    const float* __restrict__ b_ih, const float* __restrict__ b_hh,
    float* __restrict__ h2, float* __restrict__ out_hidden)
{
    __shared__ float ct_s[ENC], st_s[256], gi_s[768], gh_s[768];
    int b = blockIdx.x, t = threadIdx.x;
    for (int s = t; s < ENC; s += 256) ct_s[s] = ct[b * ENC + s];
    st_s[t] = st[b * 256 + t];
    __syncthreads();
    for (int j = t; j < 768; j += 256) {
        const float* wi = w_ih + (size_t)j * ENC;
        float si = 0.f;
        for (int k = 0; k < ENC; ++k) si += ct_s[k] * wi[k];
        const float* wh = w_hh + j * 256;
        float sh = 0.f;
        for (int k = 0; k < 256; ++k) sh += st_s[k] * wh[k];
        gi_s[j] = si + b_ih[j];
        gh_s[j] = sh + b_hh[j];
    }
    __syncthreads();
    {
        int i = t;
        float r = sigm(gi_s[i] + gh_s[i]);
        float z = sigm(gi_s[256 + i] + gh_s[256 + i]);
        float n = tanhf(gi_s[512 + i] + r * gh_s[512 + i]);
        float v = (1.f - z) * n + z * st_s[i];
        h2[b * 256 + i] = v;
        out_hidden[b * 256 + i] = v;
    }
}

// ---------------- K8: pre = h2@fc2^T + emb@emb2^T + ct@wc^T + biases ------------
__global__ __launch_bounds__(256) void k_pre(
    const float* __restrict__ h2, const float* __restrict__ emb,
    const float* __restrict__ ct,
    const float* __restrict__ fc2_w, const float* __restrict__ fc2_b,
    const float* __restrict__ emb2_w, const float* __restrict__ emb2_b,
    const float* __restrict__ wc_w, const float* __restrict__ wc_b,
    float* __restrict__ pre)
{
    int idx = blockIdx.x * 256 + threadIdx.x;  // < 2048
    int b = idx >> 7, j = idx & 127;
    float s = fc2_b[j] + emb2_b[j] + wc_b[j];
    const float* x1 = h2 + b * 256;
    const float* w1 = fc2_w + j * 256;
    for (int k = 0; k < 256; ++k) s += x1[k] * w1[k];
    const float* x2 = emb + b * 256;
    const float* w2 = emb2_w + j * 256;
    for (int k = 0; k < 256; ++k) s += x2[k] * w2[k];
    const float* x3 = ct + b * ENC;
    const float* w3 = wc_w + (size_t)j * ENC;
    for (int k = 0; k < ENC; ++k) s += x3[k] * w3[k];
    pre[idx] = s;
}

// ---------------- K9: logits = pre @ out_w^T + out_b ----------------------------
__global__ __launch_bounds__(256) void k_logits(
    const float* __restrict__ pre, const float* __restrict__ out_w,
    const float* __restrict__ out_b, float* __restrict__ logits)
{
    __shared__ float pre_s[128];
    int b = blockIdx.y;
    int j = blockIdx.x * 256 + threadIdx.x;
    if (threadIdx.x < 128) pre_s[threadIdx.x] = pre[b * 128 + threadIdx.x];
    __syncthreads();
    if (j < VOCAB) {
        const float* wr = out_w + (size_t)j * 128;
        float s = out_b[j];
        for (int k = 0; k < 128; ++k) s += pre_s[k] * wr[k];
        logits[b * VOCAB + j] = s;
    }
}

// ---------------- K10: log_softmax ----------------------------------------------
__global__ __launch_bounds__(256) void k_lsm(
    const float* __restrict__ logits, float* __restrict__ out)
{
    __shared__ float buf[VOCAB];
    __shared__ float rbuf[4];
    int b = blockIdx.x, t = threadIdx.x;
    float mx = -1e30f;
    for (int s = t; s < VOCAB; s += 256) {
        float v = logits[b * VOCAB + s];
        buf[s] = v;
        mx = fmaxf(mx, v);
    }
    for (int off = 1; off < 64; off <<= 1) mx = fmaxf(mx, __shfl_xor(mx, off, 64));
    if ((t & 63) == 0) rbuf[t >> 6] = mx;
    __syncthreads();
    mx = fmaxf(fmaxf(rbuf[0], rbuf[1]), fmaxf(rbuf[2], rbuf[3]));
    __syncthreads();
    float se = 0.f;
    for (int s = t; s < VOCAB; s += 256) se += expf(buf[s] - mx);
    for (int off = 1; off < 64; off <<= 1) se += __shfl_xor(se, off, 64);
    if ((t & 63) == 0) rbuf[t >> 6] = se;
    __syncthreads();
    float lse = mx + logf(rbuf[0] + rbuf[1] + rbuf[2] + rbuf[3]);
    for (int s = t; s < VOCAB; s += 256) out[b * VOCAB + s] = buf[s] - lse;
}

extern "C" void kernel_launch(void* const* d_in, const int* in_sizes, int n_in,
                              void* d_out, int out_size, void* d_ws, size_t ws_size,
                              hipStream_t stream)
{
    const int*   input_a      = (const int*)d_in[0];
    const float* input_hidden = (const float*)d_in[1];
    const float* enc          = (const float*)d_in[2];
    const float* att_in       = (const float*)d_in[3];
    const float* dec_att      = (const float*)d_in[4];
    const int*   h_mask       = (const int*)d_in[5];
    const int*   w_mask       = (const int*)d_in[6];
    const float* emb_w        = (const float*)d_in[11];
    const float* g1_wih       = (const float*)d_in[12];
    const float* g1_whh       = (const float*)d_in[13];
    const float* g1_bih       = (const float*)d_in[14];
    const float* g1_bhh       = (const float*)d_in[15];
    const float* fc1_w        = (const float*)d_in[16];
    const float* fc1_b        = (const float*)d_in[17];
    const float* g2_wih       = (const float*)d_in[18];
    const float* g2_whh       = (const float*)d_in[19];
    const float* g2_bih       = (const float*)d_in[20];
    const float* g2_bhh       = (const float*)d_in[21];
    const float* out_w        = (const float*)d_in[22];
    const float* out_b        = (const float*)d_in[23];
    const float* emb2_w       = (const float*)d_in[24];
    const float* emb2_b       = (const float*)d_in[25];
    const float* c1w          = (const float*)d_in[26];
    const float* c1b          = (const float*)d_in[27];
    const float* ctw          = (const float*)d_in[28];
    const float* ctb          = (const float*)d_in[29];
    const float* fc2_w        = (const float*)d_in[30];
    const float* fc2_b        = (const float*)d_in[31];
    const float* ua_w         = (const float*)d_in[32];
    const float* ua_b         = (const float*)d_in[33];
    const float* uf_w         = (const float*)d_in[34];
    const float* uf_b         = (const float*)d_in[35];
    const float* v_w          = (const float*)d_in[36];
    const float* v_b          = (const float*)d_in[37];
    const float* wc_w         = (const float*)d_in[38];
    const float* wc_b         = (const float*)d_in[39];
    const float* bn_g         = (const float*)d_in[40];
    const float* bn_b         = (const float*)d_in[41];
    const float* bn_rm        = (const float*)d_in[42];
    const float* bn_rv        = (const float*)d_in[43];

    // output layout: log_softmax(16x5000) | hidden_next(16x256) | alpha(16x2048) | att_sum(16x2048)
    float* out        = (float*)d_out;
    float* out_logits = out;
    float* out_hidden = out + 80000;
    float* out_alpha  = out + 84096;
    float* out_attsum = out + 116864;

    // workspace layout
    char* ws = (char*)d_ws;
    __hip_bfloat16* et = (__hip_bfloat16*)ws;          // 16x256x32x64 bf16 = 67,108,864 B
    float* f      = (float*)(ws + 67108864);
    float* st     = f;            // 4096
    float* embv   = f + 4096;     // 4096
    float* h1     = f + 8192;     // 4096
    float* e_acc  = f + 12288;    // 32768
    float* alpha  = f + 45056;    // 32768
    float* ct     = f + 77824;    // 16384
    float* h2     = f + 94208;    // 4096
    float* pre    = f + 98304;    // 2048
    float* logits = f + 100352;   // 80000

    hipMemsetAsync(e_acc, 0, 32768 * sizeof(float), stream);

    k_front<<<16, 256, 0, stream>>>(input_a, input_hidden, emb_w,
                                    g1_wih, g1_whh, g1_bih, g1_bhh,
                                    fc1_w, fc1_b, st, embv, h1);
    k_attsum<<<128, 256, 0, stream>>>(att_in, dec_att, c1w, c1b, out_attsum);
    k_et<<<dim3(32, 4, 16), 256, 0, stream>>>(enc, ua_w, ua_b, uf_w, uf_b,
                                              h1, out_attsum, et);
    k_conv<<<dim3(32, 4, 16), 256, 0, stream>>>(et, ctw, ctb, bn_g, bn_b,
                                                bn_rm, bn_rv, v_w, e_acc);
    k_alpha<<<16, 256, 0, stream>>>(e_acc, v_b, h_mask, w_mask, alpha, out_alpha);
    k_ct<<<dim3(256, 16), 256, 0, stream>>>(enc, alpha, ct);
    k_gru2<<<16, 256, 0, stream>>>(ct, st, g2_wih, g2_whh, g2_bih, g2_bhh,
                                   h2, out_hidden);
    k_pre<<<8, 256, 0, stream>>>(h2, embv, ct, fc2_w, fc2_b, emb2_w, emb2_b,
                                 wc_w, wc_b, pre);
    k_logits<<<dim3(20, 16), 256, 0, stream>>>(pre, out_w, out_b, logits);
    k_lsm<<<16, 256, 0, stream>>>(logits, out_logits);
}

// Round 2
// 589.641 us; speedup vs baseline: 2.3353x; 2.3353x over previous
//
#include <hip/hip_runtime.h>
#include <hip/hip_bf16.h>

#define HH 32
#define WW 64
#define HWSZ 2048
#define ENC 1024
#define VOCAB 5000

typedef __attribute__((ext_vector_type(8))) short short8;
typedef __attribute__((ext_vector_type(4))) float f32x4;

__device__ __forceinline__ float sigm(float x) { return 1.0f / (1.0f + expf(-x)); }

// round-to-nearest-even f32 -> bf16 bits
__device__ __forceinline__ unsigned short f2bf(float x) {
    unsigned u = __float_as_uint(x);
    unsigned r = (u + 0x7fff + ((u >> 16) & 1)) >> 16;
    return (unsigned short)r;
}
__device__ __forceinline__ float bf2f(unsigned short u) {
    return __uint_as_float(((unsigned)u) << 16);
}

// ---------------- K1a: gi/gh for GRU1, wide (j,b) mapping -----------------------
__global__ __launch_bounds__(256) void k_front_a(
    const int* __restrict__ input_a, const float* __restrict__ input_hidden,
    const float* __restrict__ emb_w,
    const float* __restrict__ w_ih, const float* __restrict__ w_hh,
    const float* __restrict__ b_ih, const float* __restrict__ b_hh,
    float* __restrict__ gi, float* __restrict__ gh)
{
    int gid = blockIdx.x * 256 + threadIdx.x;   // 48 blocks -> 12288 = 768*16
    int j = gid >> 4, b = gid & 15;
    int ia = input_a[b];
    const float* e  = emb_w + (size_t)ia * 256;
    const float* h0 = input_hidden + b * 256;
    const float* wi = w_ih + (size_t)j * 256;
    const float* wh = w_hh + (size_t)j * 256;
    float si = 0.f, sh = 0.f;
    for (int k = 0; k < 256; ++k) { si += e[k] * wi[k]; sh += h0[k] * wh[k]; }
    gi[j * 16 + b] = si + b_ih[j];
    gh[j * 16 + b] = sh + b_hh[j];
}

// ---------------- K1b: GRU1 gates -> st, plus emb passthrough -------------------
__global__ __launch_bounds__(256) void k_front_b(
    const int* __restrict__ input_a, const float* __restrict__ emb_w,
    const float* __restrict__ input_hidden,
    const float* __restrict__ gi, const float* __restrict__ gh,
    float* __restrict__ st, float* __restrict__ embv)
{
    int b = blockIdx.x, i = threadIdx.x;
    float r = sigm(gi[i * 16 + b] + gh[i * 16 + b]);
    float z = sigm(gi[(256 + i) * 16 + b] + gh[(256 + i) * 16 + b]);
    float n = tanhf(gi[(512 + i) * 16 + b] + r * gh[(512 + i) * 16 + b]);
    float h0 = input_hidden[b * 256 + i];
    st[b * 256 + i] = (1.f - z) * n + z * h0;
    embv[b * 256 + i] = emb_w[(size_t)input_a[b] * 256 + i];
}

// ---------------- K1c: addc[b][c] = fc1(st)[c] + ua_b[c] + uf_b[c] --------------
__global__ __launch_bounds__(256) void k_fc1(
    const float* __restrict__ st, const float* __restrict__ fc1_w,
    const float* __restrict__ fc1_b, const float* __restrict__ ua_b,
    const float* __restrict__ uf_b, float* __restrict__ addc)
{
    int gid = blockIdx.x * 256 + threadIdx.x;  // 16 blocks -> 4096 = 256*16
    int c = gid >> 4, b = gid & 15;
    const float* s = st + b * 256;
    const float* w = fc1_w + (size_t)c * 256;
    float acc = 0.f;
    for (int k = 0; k < 256; ++k) acc += s[k] * w[k];
    addc[b * 256 + c] = acc + fc1_b[c] + ua_b[c] + uf_b[c];
}

// ---------------- K2: att_sum = attention_sum + conv3x3(decoder_attention) ------
__global__ __launch_bounds__(256) void k_attsum(
    const float* __restrict__ att_in, const float* __restrict__ dec,
    const float* __restrict__ c1w, const float* __restrict__ c1b,
    float* __restrict__ out_attsum)
{
    int idx = blockIdx.x * 256 + threadIdx.x;  // < 32768
    int b = idx >> 11, hw = idx & 2047;
    int h = hw >> 6, w = hw & 63;
    float s = c1b[0];
    #pragma unroll
    for (int dy = 0; dy < 3; ++dy) {
        int hh = h + dy - 1;
        if ((unsigned)hh < (unsigned)HH) {
            #pragma unroll
            for (int dx = 0; dx < 3; ++dx) {
                int wi = w + dx - 1;
                if ((unsigned)wi < (unsigned)WW)
                    s += dec[b * HWSZ + hh * WW + wi] * c1w[dy * 3 + dx];
            }
        }
    }
    out_attsum[idx] = att_in[idx] + s;
}

// ---------------- restage: ua_w fp32 -> bf16 (same [c][k] layout) ----------------
__global__ __launch_bounds__(256) void k_ua(
    const float* __restrict__ ua_w, unsigned short* __restrict__ ub)
{
    int idx = blockIdx.x * 256 + threadIdx.x;  // 1024 blocks -> 262144
    ub[idx] = f2bf(ua_w[idx]);
}

// ---------------- restage: convtan_w [o][ci][3][3] fp32 -> w_r[tap][o][ci] bf16 --
__global__ __launch_bounds__(256) void k_wr(
    const float* __restrict__ cw, unsigned short* __restrict__ wr)
{
    int idx = blockIdx.x * 256 + threadIdx.x;  // 256 blocks -> 65536 = (o,ci)
    const float* p = cw + (size_t)idx * 9;
    #pragma unroll
    for (int t = 0; t < 9; ++t) wr[t * 65536 + idx] = f2bf(p[t]);
}

// ---------------- coef: fold conv bias + BN into scale/shift --------------------
__global__ void k_coef(
    const float* __restrict__ wb, const float* __restrict__ g,
    const float* __restrict__ bb, const float* __restrict__ rm,
    const float* __restrict__ rv, float* __restrict__ cs, float* __restrict__ csh)
{
    int c = threadIdx.x;  // 1 block x 256
    float s = g[c] * rsqrtf(rv[c] + 1e-5f);
    cs[c] = s;
    csh[c] = (wb[c] - rm[c]) * s + bb[c];
}

// ---------------- K3: et-GEMM via MFMA: et_t[b][hw][c] bf16 (NHWC) --------------
// out[c=256][hw=64/block] = ua_w[c][k=1024] @ enc[k][hw]; B transposed via LDS.
__global__ __launch_bounds__(256) void k_et(
    const float* __restrict__ enc, const unsigned short* __restrict__ ua_bf,
    const float* __restrict__ addc, const float* __restrict__ uf_w,
    const float* __restrict__ attsum, unsigned short* __restrict__ et)
{
    __shared__ unsigned short Bs[64 * 40];   // [ww][kk(32, padded to 40)]
    int t = threadIdx.x;
    int hw0 = blockIdx.x * 64, b = blockIdx.y;
    int lane = t & 63, wv = t >> 6;
    int l15 = t & 15, quad = (t >> 4) & 3;
    f32x4 acc[4][4];
    #pragma unroll
    for (int i = 0; i < 4; ++i)
        #pragma unroll
        for (int j = 0; j < 4; ++j) acc[i][j] = (f32x4)0.f;

    int sww = lane;                         // pixel this thread stages
    int skk = wv * 8;                       // k-chunk base (8 of 32)
    int sslot = ((skk >> 3) + (sww >> 3)) & 3;
    const float* encb = enc + (size_t)b * ENC * HWSZ + hw0 + sww;

    for (int k0 = 0; k0 < ENC; k0 += 32) {
        __syncthreads();
        {   // stage 32k x 64hw fp32 -> bf16 transposed into Bs[ww][kk]
            const float* ep = encb + (size_t)(k0 + skk) * HWSZ;
            short8 v;
            #pragma unroll
            for (int i = 0; i < 8; ++i) v[i] = (short)f2bf(ep[(size_t)i * HWSZ]);
            *(short8*)(Bs + sww * 40 + sslot * 8) = v;
        }
        __syncthreads();
        short8 af[4], bfr[4];
        #pragma unroll
        for (int mt = 0; mt < 4; ++mt)
            af[mt] = *(const short8*)(ua_bf +
                (size_t)(wv * 64 + mt * 16 + l15) * ENC + k0 + quad * 8);
        #pragma unroll
        for (int nt = 0; nt < 4; ++nt) {
            int n = nt * 16 + l15;
            int slot = (quad + (n >> 3)) & 3;
            bfr[nt] = *(const short8*)(Bs + n * 40 + slot * 8);
        }
        #pragma unroll
        for (int mt = 0; mt < 4; ++mt)
            #pragma unroll
            for (int nt = 0; nt < 4; ++nt)
                acc[mt][nt] = __builtin_amdgcn_mfma_f32_16x16x32_bf16(
                    af[mt], bfr[nt], acc[mt][nt], 0, 0, 0);
    }
    // epilogue: + addc[c] + attsum[hw]*uf_w[c], store NHWC bf16
    float at[4];
    #pragma unroll
    for (int nt = 0; nt < 4; ++nt) at[nt] = attsum[b * HWSZ + hw0 + nt * 16 + l15];
    #pragma unroll
    for (int mt = 0; mt < 4; ++mt) {
        int cb = wv * 64 + mt * 16 + quad * 4;
        float ad[4], uw[4];
        #pragma unroll
        for (int r = 0; r < 4; ++r) { ad[r] = addc[b * 256 + cb + r]; uw[r] = uf_w[cb + r]; }
        #pragma unroll
        for (int nt = 0; nt < 4; ++nt) {
            ushort4 pk;
            pk.x = f2bf(acc[mt][nt][0] + ad[0] + at[nt] * uw[0]);
            pk.y = f2bf(acc[mt][nt][1] + ad[1] + at[nt] * uw[1]);
            pk.z = f2bf(acc[mt][nt][2] + ad[2] + at[nt] * uw[2]);
            pk.w = f2bf(acc[mt][nt][3] + ad[3] + at[nt] * uw[3]);
            *(ushort4*)(et + (size_t)(b * HWSZ + hw0 + nt * 16 + l15) * 256 + cb) = pk;
        }
    }
}

// ---------------- K4: conv3x3 implicit-GEMM MFMA + BN + tanh + v-dot -> e -------
// Block (h, b): out [c_out 256][w 64]; B = et row in LDS (stride 264, conflict-free).
__global__ __launch_bounds__(256) void k_conv(
    const unsigned short* __restrict__ et, const unsigned short* __restrict__ wr,
    const float* __restrict__ cs, const float* __restrict__ csh,
    const float* __restrict__ v_w, float* __restrict__ e_out)
{
    __shared__ unsigned short Ls[66 * 264];  // [pixel 0..65][ci 256 pad->264]
    __shared__ float red[64][17];
    int t = threadIdx.x;
    int h = blockIdx.x, b = blockIdx.y;
    int wv = t >> 6, l15 = t & 15, quad = (t >> 4) & 3;
    f32x4 acc[4][4];
    #pragma unroll
    for (int i = 0; i < 4; ++i)
        #pragma unroll
        for (int j = 0; j < 4; ++j) acc[i][j] = (f32x4)0.f;

    for (int dy = 0; dy < 3; ++dy) {
        int hr = h + dy - 1;
        if ((unsigned)hr >= (unsigned)HH) continue;   // uniform per block
        __syncthreads();
        const unsigned short* rowp = et + (size_t)(b * HH + hr) * WW * 256;
        for (int idx = t; idx < 2112; idx += 256) {   // 66 pixels x 32 chunks
            int p = idx >> 5, s = idx & 31;
            short8 v;
            if (p == 0 || p == 65) v = (short8)0;
            else v = *(const short8*)(rowp + (p - 1) * 256 + s * 8);
            *(short8*)(Ls + p * 264 + s * 8) = v;
        }
        __syncthreads();
        for (int dx = 0; dx < 3; ++dx) {
            int tap = dy * 3 + dx;
            const unsigned short* wrt = wr + (size_t)tap * 65536;
            #pragma unroll 1
            for (int kc = 0; kc < 8; ++kc) {
                short8 af[4], bfr[4];
                #pragma unroll
                for (int mt = 0; mt < 4; ++mt)
                    af[mt] = *(const short8*)(wrt +
                        (size_t)(wv * 64 + mt * 16 + l15) * 256 + kc * 32 + quad * 8);
                #pragma unroll
                for (int nt = 0; nt < 4; ++nt) {
                    int wrow = nt * 16 + l15 + dx;     // 0..65, pads are zero
                    bfr[nt] = *(const short8*)(Ls + wrow * 264 + kc * 32 + quad * 8);
                }
                #pragma unroll
                for (int mt = 0; mt < 4; ++mt)
                    #pragma unroll
                    for (int nt = 0; nt < 4; ++nt)
                        acc[mt][nt] = __builtin_amdgcn_mfma_f32_16x16x32_bf16(
                            af[mt], bfr[nt], acc[mt][nt], 0, 0, 0);
            }
        }
    }
    // epilogue: y = acc*cs + csh; e_partial = sum tanh(y)*v_w over this lane's c
    float p[4] = {0.f, 0.f, 0.f, 0.f};
    #pragma unroll
    for (int mt = 0; mt < 4; ++mt) {
        int cb = wv * 64 + mt * 16 + quad * 4;
        #pragma unroll
        for (int r = 0; r < 4; ++r) {
            float sc = cs[cb + r], sh = csh[cb + r], vw = v_w[cb + r];
            #pragma unroll
            for (int nt = 0; nt < 4; ++nt) {
                float x = acc[mt][nt][r] * sc + sh;
                p[nt] += tanhf(x) * vw;
            }
        }
    }
    __syncthreads();
    #pragma unroll
    for (int nt = 0; nt < 4; ++nt) red[nt * 16 + l15][wv * 4 + quad] = p[nt];
    __syncthreads();
    if (t < 64) {
        float s = 0.f;
        #pragma unroll
        for (int i = 0; i < 16; ++i) s += red[t][i];
        e_out[(b * HH + h) * WW + t] = s;
    }
}

// ---------------- K5: softmax over masked e -> alpha ----------------------------
__global__ __launch_bounds__(256) void k_alpha(
    const float* __restrict__ e_acc, const float* __restrict__ v_b,
    const int* __restrict__ h_mask, const int* __restrict__ w_mask,
    float* __restrict__ alpha_ws, float* __restrict__ alpha_out)
{
    __shared__ float rbuf[4];
    int b = blockIdx.x, t = threadIdx.x;
    int hm = h_mask[b], wm = w_mask[b];
    float vb = v_b[0];
    float vals[8];
    float psum = 0.f;
    #pragma unroll
    for (int u = 0; u < 8; ++u) {
        int s = u * 256 + t;
        int h = s >> 6, w = s & 63;
        float e = e_acc[b * HWSZ + s] + vb;
        float ex = (h < hm && w < wm) ? expf(e) : 0.f;
        vals[u] = ex;
        psum += ex;
    }
    for (int off = 1; off < 64; off <<= 1) psum += __shfl_xor(psum, off, 64);
    if ((t & 63) == 0) rbuf[t >> 6] = psum;
    __syncthreads();
    float tot = rbuf[0] + rbuf[1] + rbuf[2] + rbuf[3] + 1e-8f;
    float inv = 1.f / tot;
    #pragma unroll
    for (int u = 0; u < 8; ++u) {
        int s = u * 256 + t;
        float a = vals[u] * inv;
        alpha_ws[b * HWSZ + s] = a;
        alpha_out[b * HWSZ + s] = a;
    }
}

// ---------------- K6: ct[b,c] = sum_hw alpha * enc  (wave per channel) ----------
__global__ __launch_bounds__(256) void k_ct(
    const float* __restrict__ enc, const float* __restrict__ alpha,
    float* __restrict__ ct)
{
    __shared__ float a_s[HWSZ];
    int b = blockIdx.y, cg = blockIdx.x, t = threadIdx.x;
    for (int s = t; s < HWSZ; s += 256) a_s[s] = alpha[b * HWSZ + s];
    __syncthreads();
    int wave = t >> 6, lane = t & 63;
    int c = cg * 4 + wave;
    const float* ep = enc + ((size_t)(b * ENC + c)) * HWSZ;
    float s = 0.f;
    for (int i = lane; i < HWSZ; i += 64) s += ep[i] * a_s[i];
    for (int off = 32; off; off >>= 1) s += __shfl_down(s, off, 64);
    if (lane == 0) ct[b * ENC + c] = s;
}

// ---------------- K7a: gi/gh for GRU2, wide (j,b) mapping -----------------------
__global__ __launch_bounds__(256) void k_gru2a(
    const float* __restrict__ ct, const float* __restrict__ st,
    const float* __restrict__ w_ih, const float* __restrict__ w_hh,
    const float* __restrict__ b_ih, const float* __restrict__ b_hh,
    float* __restrict__ gi, float* __restrict__ gh)
{
    int gid = blockIdx.x * 256 + threadIdx.x;  // 48 blocks
    int j = gid >> 4, b = gid & 15;
    const float* c = ct + b * ENC;
    const float* wi = w_ih + (size_t)j * ENC;
    float si = 0.f;
    for (int k = 0; k < ENC; ++k) si += c[k] * wi[k];
    const float* s = st + b * 256;
    const float* wh = w_hh + (size_t)j * 256;
    float sh = 0.f;
    for (int k = 0; k < 256; ++k) sh += s[k] * wh[k];
    gi[j * 16 + b] = si + b_ih[j];
    gh[j * 16 + b] = sh + b_hh[j];
}

// ---------------- K7b: GRU2 gates -> h2 / hidden_next ---------------------------
__global__ __launch_bounds__(256) void k_gru2b(
    const float* __restrict__ st, const float* __restrict__ gi,
    const float* __restrict__ gh, float* __restrict__ h2,
    float* __restrict__ out_hidden)
{
    int b = blockIdx.x, i = threadIdx.x;
    float r = sigm(gi[i * 16 + b] + gh[i * 16 + b]);
    float z = sigm(gi[(256 + i) * 16 + b] + gh[(256 + i) * 16 + b]);
    float n = tanhf(gi[(512 + i) * 16 + b] + r * gh[(512 + i) * 16 + b]);
    float v = (1.f - z) * n + z * st[b * 256 + i];
    h2[b * 256 + i] = v;
    out_hidden[b * 256 + i] = v;
}

// ---------------- K8: pre = h2@fc2^T + emb@emb2^T + ct@wc^T + biases ------------
__global__ __launch_bounds__(256) void k_pre(
    const float* __restrict__ h2, const float* __restrict__ emb,
    const float* __restrict__ ct,
    const float* __restrict__ fc2_w, const float* __restrict__ fc2_b,
    const float* __restrict__ emb2_w, const float* __restrict__ emb2_b,
    const float* __restrict__ wc_w, const float* __restrict__ wc_b,
    float* __restrict__ pre)
{
    int gid = blockIdx.x * 256 + threadIdx.x;  // 8 blocks -> 2048 = 128*16
    int j = gid >> 4, b = gid & 15;
    float s = fc2_b[j] + emb2_b[j] + wc_b[j];
    const float* x1 = h2 + b * 256;
    const float* w1 = fc2_w + (size_t)j * 256;
    for (int k = 0; k < 256; ++k) s += x1[k] * w1[k];
    const float* x2 = emb + b * 256;
    const float* w2 = emb2_w + (size_t)j * 256;
    for (int k = 0; k < 256; ++k) s += x2[k] * w2[k];
    const float* x3 = ct + b * ENC;
    const float* w3 = wc_w + (size_t)j * ENC;
    for (int k = 0; k < ENC; ++k) s += x3[k] * w3[k];
    pre[b * 128 + j] = s;
}

// ---------------- K9: logits = pre @ out_w^T + out_b, wide (j,b) ----------------
__global__ __launch_bounds__(256) void k_logits(
    const float* __restrict__ pre, const float* __restrict__ out_w,
    const float* __restrict__ out_b, float* __restrict__ logits)
{
    int gid = blockIdx.x * 256 + threadIdx.x;  // 313 blocks
    int j = gid >> 4, b = gid & 15;
    if (j >= VOCAB) return;
    const float* wr = out_w + (size_t)j * 128;
    const float* p = pre + b * 128;
    float s = out_b[j];
    for (int k = 0; k < 128; ++k) s += p[k] * wr[k];
    logits[b * VOCAB + j] = s;
}

// ---------------- K10: log_softmax ----------------------------------------------
__global__ __launch_bounds__(256) void k_lsm(
    const float* __restrict__ logits, float* __restrict__ out)
{
    __shared__ float buf[VOCAB];
    __shared__ float rbuf[4];
    int b = blockIdx.x, t = threadIdx.x;
    float mx = -1e30f;
    for (int s = t; s < VOCAB; s += 256) {
        float v = logits[b * VOCAB + s];
        buf[s] = v;
        mx = fmaxf(mx, v);
    }
    for (int off = 1; off < 64; off <<= 1) mx = fmaxf(mx, __shfl_xor(mx, off, 64));
    if ((t & 63) == 0) rbuf[t >> 6] = mx;
    __syncthreads();
    mx = fmaxf(fmaxf(rbuf[0], rbuf[1]), fmaxf(rbuf[2], rbuf[3]));
    __syncthreads();
    float se = 0.f;
    for (int s = t; s < VOCAB; s += 256) se += expf(buf[s] - mx);
    for (int off = 1; off < 64; off <<= 1) se += __shfl_xor(se, off, 64);
    if ((t & 63) == 0) rbuf[t >> 6] = se;
    __syncthreads();
    float lse = mx + logf(rbuf[0] + rbuf[1] + rbuf[2] + rbuf[3]);
    for (int s = t; s < VOCAB; s += 256) out[b * VOCAB + s] = buf[s] - lse;
}

extern "C" void kernel_launch(void* const* d_in, const int* in_sizes, int n_in,
                              void* d_out, int out_size, void* d_ws, size_t ws_size,
                              hipStream_t stream)
{
    const int*   input_a      = (const int*)d_in[0];
    const float* input_hidden = (const float*)d_in[1];
    const float* enc          = (const float*)d_in[2];
    const float* att_in       = (const float*)d_in[3];
    const float* dec_att      = (const float*)d_in[4];
    const int*   h_mask       = (const int*)d_in[5];
    const int*   w_mask       = (const int*)d_in[6];
    const float* emb_w        = (const float*)d_in[11];
    const float* g1_wih       = (const float*)d_in[12];
    const float* g1_whh       = (const float*)d_in[13];
    const float* g1_bih       = (const float*)d_in[14];
    const float* g1_bhh       = (const float*)d_in[15];
    const float* fc1_w        = (const float*)d_in[16];
    const float* fc1_b        = (const float*)d_in[17];
    const float* g2_wih       = (const float*)d_in[18];
    const float* g2_whh       = (const float*)d_in[19];
    const float* g2_bih       = (const float*)d_in[20];
    const float* g2_bhh       = (const float*)d_in[21];
    const float* out_w        = (const float*)d_in[22];
    const float* out_b        = (const float*)d_in[23];
    const float* emb2_w       = (const float*)d_in[24];
    const float* emb2_b       = (const float*)d_in[25];
    const float* c1w          = (const float*)d_in[26];
    const float* c1b          = (const float*)d_in[27];
    const float* ctw          = (const float*)d_in[28];
    const float* ctb          = (const float*)d_in[29];
    const float* fc2_w        = (const float*)d_in[30];
    const float* fc2_b        = (const float*)d_in[31];
    const float* ua_w         = (const float*)d_in[32];
    const float* ua_b         = (const float*)d_in[33];
    const float* uf_w         = (const float*)d_in[34];
    const float* uf_b         = (const float*)d_in[35];
    const float* v_w          = (const float*)d_in[36];
    const float* v_b          = (const float*)d_in[37];
    const float* wc_w         = (const float*)d_in[38];
    const float* wc_b         = (const float*)d_in[39];
    const float* bn_g         = (const float*)d_in[40];
    const float* bn_b         = (const float*)d_in[41];
    const float* bn_rm        = (const float*)d_in[42];
    const float* bn_rv        = (const float*)d_in[43];

    // output layout: log_softmax(16x5000) | hidden_next(16x256) | alpha(16x2048) | att_sum(16x2048)
    float* out        = (float*)d_out;
    float* out_logits = out;
    float* out_hidden = out + 80000;
    float* out_alpha  = out + 84096;
    float* out_attsum = out + 116864;

    // workspace layout
    char* ws = (char*)d_ws;
    unsigned short* et_t  = (unsigned short*)ws;                 // 16.78 MB (NHWC bf16)
    unsigned short* ua_bf = (unsigned short*)(ws + 16777216);    // 0.52 MB
    unsigned short* w_r   = (unsigned short*)(ws + 17301504);    // 1.18 MB
    float* f      = (float*)(ws + 18481152);
    float* st     = f;             // 4096
    float* embv   = f + 4096;      // 4096
    float* addc   = f + 8192;      // 4096
    float* e_ws   = f + 12288;     // 32768
    float* alpha  = f + 45056;     // 32768
    float* ct     = f + 77824;     // 16384
    float* h2     = f + 94208;     // 4096
    float* pre    = f + 98304;     // 2048
    float* logits = f + 100352;    // 80000
    float* gi1    = f + 180352;    // 12288
    float* gh1    = f + 192640;    // 12288
    float* gi2    = f + 204928;    // 12288
    float* gh2    = f + 217216;    // 12288
    float* cs     = f + 229504;    // 256
    float* csh    = f + 229760;    // 256

    // independent restages first
    k_ua<<<1024, 256, 0, stream>>>(ua_w, ua_bf);
    k_wr<<<256, 256, 0, stream>>>(ctw, w_r);
    k_coef<<<1, 256, 0, stream>>>(ctb, bn_g, bn_b, bn_rm, bn_rv, cs, csh);
    k_attsum<<<128, 256, 0, stream>>>(att_in, dec_att, c1w, c1b, out_attsum);

    // front path
    k_front_a<<<48, 256, 0, stream>>>(input_a, input_hidden, emb_w,
                                      g1_wih, g1_whh, g1_bih, g1_bhh, gi1, gh1);
    k_front_b<<<16, 256, 0, stream>>>(input_a, emb_w, input_hidden, gi1, gh1, st, embv);
    k_fc1<<<16, 256, 0, stream>>>(st, fc1_w, fc1_b, ua_b, uf_b, addc);

    // big MFMA kernels
    k_et<<<dim3(32, 16), 256, 0, stream>>>(enc, ua_bf, addc, uf_w, out_attsum, et_t);
    k_conv<<<dim3(32, 16), 256, 0, stream>>>(et_t, w_r, cs, csh, v_w, e_ws);

    // attention + tail
    k_alpha<<<16, 256, 0, stream>>>(e_ws, v_b, h_mask, w_mask, alpha, out_alpha);
    k_ct<<<dim3(256, 16), 256, 0, stream>>>(enc, alpha, ct);
    k_gru2a<<<48, 256, 0, stream>>>(ct, st, g2_wih, g2_whh, g2_bih, g2_bhh, gi2, gh2);
    k_gru2b<<<16, 256, 0, stream>>>(st, gi2, gh2, h2, out_hidden);
    k_pre<<<8, 256, 0, stream>>>(h2, embv, ct, fc2_w, fc2_b, emb2_w, emb2_b,
                                 wc_w, wc_b, pre);
    k_logits<<<313, 256, 0, stream>>>(pre, out_w, out_b, logits);
    k_lsm<<<16, 256, 0, stream>>>(logits, out_logits);
}